// Round 1
// baseline (4383.606 us; speedup 1.0000x reference)
//
#include <hip/hip_runtime.h>
#include <hip/hip_bf16.h>
#include <math.h>

// ---- constants ----
#define BB    32
#define DD    768
#define LL    12
#define HH    12
#define NN    196
#define DHH   64
#define FFF   3072
#define MM    (BB * NN)      // 6272 tokens
#define BHH   (BB * HH)      // 384

typedef float  floatx4 __attribute__((ext_vector_type(4)));
typedef __bf16 bf16x8  __attribute__((ext_vector_type(8)));

#define DEV __device__ __forceinline__

DEV unsigned short bf16u(float v) {
  __hip_bfloat16 h = __float2bfloat16(v);
  return __builtin_bit_cast(unsigned short, h);
}

DEV floatx4 mfma_bf16(bf16x8 a, bf16x8 b, floatx4 c) {
  return __builtin_amdgcn_mfma_f32_16x16x32_bf16(a, b, c, 0, 0, 0);
}

DEV void gl2lds16(const void* g, void* l) {
  __builtin_amdgcn_global_load_lds(
      (const __attribute__((address_space(1))) void*)g,
      (__attribute__((address_space(3))) void*)l, 16, 0, 0);
}

// ---- fp32 -> bf16 conversion (vectorized) ----
__global__ __launch_bounds__(256) void cvt4_k(const float4* __restrict__ in,
                                              ushort4* __restrict__ out, int n4) {
  int i = blockIdx.x * 256 + threadIdx.x;
  if (i < n4) {
    float4 v = in[i];
    ushort4 o;
    o.x = bf16u(v.x); o.y = bf16u(v.y); o.z = bf16u(v.z); o.w = bf16u(v.w);
    out[i] = o;
  }
}

// ---- im2col for patch embed: x (32,3,224,224) -> A (6272, 768) bf16 ----
__global__ __launch_bounds__(256) void im2col_k(const float* __restrict__ x,
                                                unsigned short* __restrict__ A) {
  int idx = blockIdx.x * 256 + threadIdx.x;      // grid covers 6272*768 exactly
  int col = idx % DD;
  int token = idx / DD;
  int b = token / NN, p = token % NN;
  int pr = p / 14, pc = p % 14;
  int c = col >> 8, rm = col & 255, i = rm >> 4, j = rm & 15;
  float v = x[(((size_t)b * 3 + c) * 224 + pr * 16 + i) * 224 + pc * 16 + j];
  A[idx] = bf16u(v);
}

// ---- LayerNorm: h fp32 (M,768) -> out (bf16 or fp32) ----
template <int F32OUT>
__global__ __launch_bounds__(256) void ln_k(const float* __restrict__ x,
                                            const float* __restrict__ w,
                                            const float* __restrict__ bb,
                                            void* __restrict__ outp) {
  const int token = blockIdx.x, tid = threadIdx.x;
  const float* xr = x + (size_t)token * DD;
  float v0 = xr[tid], v1 = xr[tid + 256], v2 = xr[tid + 512];
  float s = v0 + v1 + v2;
  float ss = v0 * v0 + v1 * v1 + v2 * v2;
#pragma unroll
  for (int off = 32; off; off >>= 1) {
    s += __shfl_down(s, off);
    ss += __shfl_down(ss, off);
  }
  __shared__ float rs[4], rq[4];
  if ((tid & 63) == 0) { rs[tid >> 6] = s; rq[tid >> 6] = ss; }
  __syncthreads();
  float tot = rs[0] + rs[1] + rs[2] + rs[3];
  float tq  = rq[0] + rq[1] + rq[2] + rq[3];
  const float mean = tot * (1.0f / 768.0f);
  const float var  = tq * (1.0f / 768.0f) - mean * mean;
  const float rstd = rsqrtf(var + 1e-5f);
#pragma unroll
  for (int t = 0; t < 3; t++) {
    int col = tid + t * 256;
    float xv = (t == 0) ? v0 : (t == 1 ? v1 : v2);
    float yv = (xv - mean) * rstd * w[col] + bb[col];
    if (F32OUT) ((float*)outp)[(size_t)token * DD + col] = yv;
    else        ((unsigned short*)outp)[(size_t)token * DD + col] = bf16u(yv);
  }
}

// ---- GEMM: C(M x Nn) = A(M x K) @ W(Nn x K)^T, bf16 inputs, fp32 accum ----
// MODE 0: out bf16 = acc + bias
// MODE 1: out fp32 = acc + bias + pos[(row%196)*Nn + col]   (patch embed)
// MODE 2: out fp32 += acc + bias                            (residual)
// MODE 3: out bf16 = gelu(acc + bias)                       (fc1)
template <int MODE>
__global__ __launch_bounds__(256, 2) void gemm_bt(
    const unsigned short* __restrict__ A, const unsigned short* __restrict__ W,
    const float* __restrict__ bias, const float* __restrict__ aux,
    void* __restrict__ outp, int K, int Nn) {
  __shared__ unsigned short As[128 * 32];
  __shared__ unsigned short Bs[128 * 32];
  const int tid = threadIdx.x;
  const int wave = tid >> 6, lane = tid & 63;
  const int tm = blockIdx.y * 128, tn = blockIdx.x * 128;
  const int wm = (wave >> 1) * 64, wn = (wave & 1) * 64;
  const int lr = lane & 15, k8 = (lane >> 4) * 8;
  const int c0 = tid, c1 = tid + 256;          // 16B chunks of the 128x32 tile
  const size_t ga0 = (size_t)(tm + (c0 >> 2)) * K + (c0 & 3) * 8;
  const size_t ga1 = (size_t)(tm + (c1 >> 2)) * K + (c1 & 3) * 8;
  const size_t gb0 = (size_t)(tn + (c0 >> 2)) * K + (c0 & 3) * 8;
  const size_t gb1 = (size_t)(tn + (c1 >> 2)) * K + (c1 & 3) * 8;
  floatx4 acc[4][4] = {};
  for (int k0 = 0; k0 < K; k0 += 32) {
    gl2lds16(A + ga0 + k0, &As[c0 * 8]);
    gl2lds16(A + ga1 + k0, &As[c1 * 8]);
    gl2lds16(W + gb0 + k0, &Bs[c0 * 8]);
    gl2lds16(W + gb1 + k0, &Bs[c1 * 8]);
    __syncthreads();
    bf16x8 af[4], bq[4];
#pragma unroll
    for (int mi = 0; mi < 4; mi++)
      af[mi] = *(const bf16x8*)&As[(wm + mi * 16 + lr) * 32 + k8];
#pragma unroll
    for (int ni = 0; ni < 4; ni++)
      bq[ni] = *(const bf16x8*)&Bs[(wn + ni * 16 + lr) * 32 + k8];
#pragma unroll
    for (int mi = 0; mi < 4; mi++)
#pragma unroll
      for (int ni = 0; ni < 4; ni++)
        acc[mi][ni] = mfma_bf16(af[mi], bq[ni], acc[mi][ni]);
    __syncthreads();
  }
  const int rbase = tm + wm + (lane >> 4) * 4;
  const int cbase = tn + wn + lr;
#pragma unroll
  for (int ni = 0; ni < 4; ni++) {
    const int col = cbase + ni * 16;
    const float bv = bias[col];
#pragma unroll
    for (int mi = 0; mi < 4; mi++) {
#pragma unroll
      for (int r = 0; r < 4; r++) {
        const int row = rbase + mi * 16 + r;
        float v = acc[mi][ni][r] + bv;
        if (MODE == 0) {
          ((unsigned short*)outp)[(size_t)row * Nn + col] = bf16u(v);
        } else if (MODE == 1) {
          ((float*)outp)[(size_t)row * Nn + col] =
              v + aux[(size_t)(row % NN) * Nn + col];
        } else if (MODE == 2) {
          float* hp = (float*)outp + (size_t)row * Nn + col;
          *hp += v;
        } else {
          float g = 0.5f * v * (1.0f + erff(v * 0.70710678118654752f));
          ((unsigned short*)outp)[(size_t)row * Nn + col] = bf16u(g);
        }
      }
    }
  }
}

// ---- attention scores: S[bh][i][j] = 0.125 * sum_d Q[b,i,h,d] K[b,j,h,d] ----
__global__ __launch_bounds__(256) void scores_k(const unsigned short* __restrict__ qkv,
                                                float* __restrict__ S) {
  const int bh = blockIdx.x;
  const int b = bh / HH, hh = bh % HH;
  const int i0 = (blockIdx.y / 7) * 32, j0 = (blockIdx.y % 7) * 32;
  const int w = threadIdx.x >> 6, lane = threadIdx.x & 63;
  const int ti = i0 + (w >> 1) * 16, tj = j0 + (w & 1) * 16;
  const int lr = lane & 15, k8 = (lane >> 4) * 8;
  const int iq = min(ti + lr, NN - 1), jk = min(tj + lr, NN - 1);
  const unsigned short* qb = qkv + (size_t)(b * NN + iq) * 2304 + hh * 64 + k8;
  const unsigned short* kb = qkv + (size_t)(b * NN + jk) * 2304 + 768 + hh * 64 + k8;
  floatx4 acc = {0.f, 0.f, 0.f, 0.f};
  acc = mfma_bf16(*(const bf16x8*)qb, *(const bf16x8*)kb, acc);
  acc = mfma_bf16(*(const bf16x8*)(qb + 32), *(const bf16x8*)(kb + 32), acc);
  float* Sb = S + (size_t)bh * NN * NN;
#pragma unroll
  for (int r = 0; r < 4; r++) {
    int i = ti + (lane >> 4) * 4 + r, j = tj + lr;
    if (i < NN && j < NN) Sb[(size_t)i * NN + j] = acc[r] * 0.125f;
  }
}

// ---- softmax rows -> P bf16 padded to 224 cols (zeros past 196) ----
__global__ __launch_bounds__(256) void softmax_k(const float* __restrict__ S,
                                                 unsigned short* __restrict__ P) {
  const int r = blockIdx.x * 4 + (threadIdx.x >> 6);
  const int lane = threadIdx.x & 63;
  const float* row = S + (size_t)r * NN;
  float v[4];
#pragma unroll
  for (int t = 0; t < 4; t++) {
    int j = lane + t * 64;
    v[t] = (j < NN) ? row[j] : -1e30f;
  }
  float m = fmaxf(fmaxf(v[0], v[1]), fmaxf(v[2], v[3]));
#pragma unroll
  for (int off = 32; off; off >>= 1) m = fmaxf(m, __shfl_xor(m, off));
  float e[4], s = 0.f;
#pragma unroll
  for (int t = 0; t < 4; t++) {
    int j = lane + t * 64;
    e[t] = (j < NN) ? __expf(v[t] - m) : 0.f;
    s += e[t];
  }
#pragma unroll
  for (int off = 32; off; off >>= 1) s += __shfl_xor(s, off);
  const float inv = 1.0f / s;
  unsigned short* prow = P + (size_t)r * 224;
#pragma unroll
  for (int t = 0; t < 4; t++) {
    int j = lane + t * 64;
    if (j < 224) prow[j] = bf16u(e[t] * inv);
  }
}

// ---- V transpose: Vt[bh][d][jp] = V[b,j,h,d], zero for j>=196 ----
__global__ __launch_bounds__(256) void vt_k(const unsigned short* __restrict__ qkv,
                                            unsigned short* __restrict__ Vt) {
  int idx = blockIdx.x * 256 + threadIdx.x;     // 384*64*224 exactly
  int j = idx % 224;
  int rest = idx / 224;
  int d = rest % 64, bh = rest / 64;
  int b = bh / HH, hh = bh % HH;
  unsigned short val = 0;
  if (j < NN) val = qkv[(size_t)(b * NN + j) * 2304 + 1536 + hh * 64 + d];
  Vt[idx] = val;
}

// ---- PV: o[b,i, h*64+d] = sum_j P[bh][i][j] * Vt[bh][d][j] ----
__global__ __launch_bounds__(256) void pv_k(const unsigned short* __restrict__ P,
                                            const unsigned short* __restrict__ Vt,
                                            unsigned short* __restrict__ o) {
  const int bh = blockIdx.x;
  const int b = bh / HH, hh = bh % HH;
  const int t = blockIdx.y * 4 + (threadIdx.x >> 6);
  const int it = t >> 2, dt = t & 3;
  const int lane = threadIdx.x & 63, lr = lane & 15, k8 = (lane >> 4) * 8;
  const int ip = min(it * 16 + lr, NN - 1);
  const unsigned short* pb = P + ((size_t)bh * NN + ip) * 224 + k8;
  const unsigned short* vb = Vt + ((size_t)bh * 64 + dt * 16 + lr) * 224 + k8;
  floatx4 acc = {0.f, 0.f, 0.f, 0.f};
#pragma unroll
  for (int k0 = 0; k0 < 224; k0 += 32)
    acc = mfma_bf16(*(const bf16x8*)(pb + k0), *(const bf16x8*)(vb + k0), acc);
#pragma unroll
  for (int r = 0; r < 4; r++) {
    int i = it * 16 + (lane >> 4) * 4 + r;
    if (i < NN)
      o[(size_t)(b * NN + i) * DD + hh * 64 + dt * 16 + lr] = bf16u(acc[r]);
  }
}

extern "C" void kernel_launch(void* const* d_in, const int* in_sizes, int n_in,
                              void* d_out, int out_size, void* d_ws, size_t ws_size,
                              hipStream_t stream) {
  const float* x       = (const float*)d_in[0];
  const float* patchw  = (const float*)d_in[1];
  const float* patchb  = (const float*)d_in[2];
  const float* pos     = (const float*)d_in[3];
  const float* ln1w    = (const float*)d_in[4];
  const float* ln1b    = (const float*)d_in[5];
  const float* qkvw    = (const float*)d_in[6];
  const float* qkvb    = (const float*)d_in[7];
  const float* projw   = (const float*)d_in[8];
  const float* projb   = (const float*)d_in[9];
  const float* ln2w    = (const float*)d_in[10];
  const float* ln2b    = (const float*)d_in[11];
  const float* fc1w    = (const float*)d_in[12];
  const float* fc1b    = (const float*)d_in[13];
  const float* fc2w    = (const float*)d_in[14];
  const float* fc2b    = (const float*)d_in[15];
  const float* lnfw    = (const float*)d_in[16];
  const float* lnfb    = (const float*)d_in[17];

  char* base = (char*)d_ws;
  size_t off = 0;
  auto alloc = [&](size_t bytes) {
    void* p = base + off;
    off = (off + bytes + 255) & ~(size_t)255;
    return p;
  };
  unsigned short* Wq  = (unsigned short*)alloc((size_t)LL * 2304 * 768 * 2);
  unsigned short* Wp  = (unsigned short*)alloc((size_t)LL * 768 * 768 * 2);
  unsigned short* W1  = (unsigned short*)alloc((size_t)LL * 3072 * 768 * 2);
  unsigned short* W2  = (unsigned short*)alloc((size_t)LL * 768 * 3072 * 2);
  unsigned short* Wpe = (unsigned short*)alloc((size_t)768 * 768 * 2);
  float*          h   = (float*)alloc((size_t)MM * DD * 4);
  unsigned short* y   = (unsigned short*)alloc((size_t)MM * DD * 2);
  unsigned short* qkv = (unsigned short*)alloc((size_t)MM * 2304 * 2);
  float*          S   = (float*)alloc((size_t)BHH * NN * NN * 4);   // aliased w/ g
  unsigned short* g   = (unsigned short*)S;                         // fc1 out (38.5MB <= 59MB)
  unsigned short* P   = (unsigned short*)alloc((size_t)BHH * NN * 224 * 2);
  unsigned short* Vt  = (unsigned short*)alloc((size_t)BHH * 64 * 224 * 2);
  unsigned short* o   = (unsigned short*)alloc((size_t)MM * DD * 2);
  if (off > ws_size) return;  // workspace too small: fail loudly (wrong output)

  unsigned short* Aim = qkv;  // im2col buffer aliases qkv (dead by layer 0)

  auto cvt = [&](const float* src, unsigned short* dst, size_t n) {
    int n4 = (int)(n / 4);
    cvt4_k<<<dim3((n4 + 255) / 256), dim3(256), 0, stream>>>(
        (const float4*)src, (ushort4*)dst, n4);
  };
  cvt(qkvw, Wq, (size_t)LL * 2304 * 768);
  cvt(projw, Wp, (size_t)LL * 768 * 768);
  cvt(fc1w, W1, (size_t)LL * 3072 * 768);
  cvt(fc2w, W2, (size_t)LL * 768 * 3072);
  cvt(patchw, Wpe, (size_t)768 * 768);

  im2col_k<<<dim3(MM * DD / 256), dim3(256), 0, stream>>>(x, Aim);
  // patch embed GEMM: h = Aim @ Wpe^T + patch_b + pos
  gemm_bt<1><<<dim3(6, 49), dim3(256), 0, stream>>>(Aim, Wpe, patchb, pos, h, 768, 768);

  for (int l = 0; l < LL; l++) {
    ln_k<0><<<dim3(MM), dim3(256), 0, stream>>>(h, ln1w + l * 768, ln1b + l * 768, y);
    gemm_bt<0><<<dim3(18, 49), dim3(256), 0, stream>>>(
        y, Wq + (size_t)l * 2304 * 768, qkvb + l * 2304, nullptr, qkv, 768, 2304);
    scores_k<<<dim3(BHH, 49), dim3(256), 0, stream>>>(qkv, S);
    softmax_k<<<dim3(BHH * NN / 4), dim3(256), 0, stream>>>(S, P);
    vt_k<<<dim3(BHH * 64 * 224 / 256), dim3(256), 0, stream>>>(qkv, Vt);
    pv_k<<<dim3(BHH, 13), dim3(256), 0, stream>>>(P, Vt, o);
    gemm_bt<2><<<dim3(6, 49), dim3(256), 0, stream>>>(
        o, Wp + (size_t)l * 768 * 768, projb + l * 768, nullptr, h, 768, 768);
    ln_k<0><<<dim3(MM), dim3(256), 0, stream>>>(h, ln2w + l * 768, ln2b + l * 768, y);
    gemm_bt<3><<<dim3(24, 49), dim3(256), 0, stream>>>(
        y, W1 + (size_t)l * 3072 * 768, fc1b + l * 3072, nullptr, g, 768, 3072);
    gemm_bt<2><<<dim3(6, 49), dim3(256), 0, stream>>>(
        g, W2 + (size_t)l * 768 * 3072, fc2b + l * 768, nullptr, h, 3072, 768);
  }
  ln_k<1><<<dim3(MM), dim3(256), 0, stream>>>(h, lnfw, lnfb, d_out);
}

// Round 2
// 4308.544 us; speedup vs baseline: 1.0174x; 1.0174x over previous
//
#include <hip/hip_runtime.h>
#include <hip/hip_bf16.h>
#include <math.h>

// ---- constants ----
#define BB    32
#define DD    768
#define LL    12
#define HH    12
#define NN    196
#define DHH   64
#define FFF   3072
#define MM    (BB * NN)      // 6272 tokens
#define BHH   (BB * HH)      // 384

typedef float  floatx4 __attribute__((ext_vector_type(4)));
typedef __bf16 bf16x8  __attribute__((ext_vector_type(8)));

#define DEV __device__ __forceinline__

DEV unsigned short bf16u(float v) {
  __hip_bfloat16 h = __float2bfloat16(v);
  return __builtin_bit_cast(unsigned short, h);
}

DEV floatx4 mfma_bf16(bf16x8 a, bf16x8 b, floatx4 c) {
  return __builtin_amdgcn_mfma_f32_16x16x32_bf16(a, b, c, 0, 0, 0);
}

DEV void gl2lds16(const void* g, void* l) {
  __builtin_amdgcn_global_load_lds(
      (const __attribute__((address_space(1))) void*)g,
      (__attribute__((address_space(3))) void*)l, 16, 0, 0);
}

// ---- fp32 -> bf16 conversion (vectorized) ----
__global__ __launch_bounds__(256) void cvt4_k(const float4* __restrict__ in,
                                              ushort4* __restrict__ out, int n4) {
  int i = blockIdx.x * 256 + threadIdx.x;
  if (i < n4) {
    float4 v = in[i];
    ushort4 o;
    o.x = bf16u(v.x); o.y = bf16u(v.y); o.z = bf16u(v.z); o.w = bf16u(v.w);
    out[i] = o;
  }
}

// ---- im2col for patch embed: x (32,3,224,224) -> A (6272, 768) bf16 ----
__global__ __launch_bounds__(256) void im2col_k(const float* __restrict__ x,
                                                unsigned short* __restrict__ A) {
  int idx = blockIdx.x * 256 + threadIdx.x;      // grid covers 6272*768 exactly
  int col = idx % DD;
  int token = idx / DD;
  int b = token / NN, p = token % NN;
  int pr = p / 14, pc = p % 14;
  int c = col >> 8, rm = col & 255, i = rm >> 4, j = rm & 15;
  float v = x[(((size_t)b * 3 + c) * 224 + pr * 16 + i) * 224 + pc * 16 + j];
  A[idx] = bf16u(v);
}

// ---- LayerNorm: h fp32 (M,768) -> out (bf16 or fp32) ----
template <int F32OUT>
__global__ __launch_bounds__(256) void ln_k(const float* __restrict__ x,
                                            const float* __restrict__ w,
                                            const float* __restrict__ bb,
                                            void* __restrict__ outp) {
  const int token = blockIdx.x, tid = threadIdx.x;
  const float* xr = x + (size_t)token * DD;
  float v0 = xr[tid], v1 = xr[tid + 256], v2 = xr[tid + 512];
  float s = v0 + v1 + v2;
  float ss = v0 * v0 + v1 * v1 + v2 * v2;
#pragma unroll
  for (int off = 32; off; off >>= 1) {
    s += __shfl_down(s, off);
    ss += __shfl_down(ss, off);
  }
  __shared__ float rs[4], rq[4];
  if ((tid & 63) == 0) { rs[tid >> 6] = s; rq[tid >> 6] = ss; }
  __syncthreads();
  float tot = rs[0] + rs[1] + rs[2] + rs[3];
  float tq  = rq[0] + rq[1] + rq[2] + rq[3];
  const float mean = tot * (1.0f / 768.0f);
  const float var  = tq * (1.0f / 768.0f) - mean * mean;
  const float rstd = rsqrtf(var + 1e-5f);
#pragma unroll
  for (int t = 0; t < 3; t++) {
    int col = tid + t * 256;
    float xv = (t == 0) ? v0 : (t == 1 ? v1 : v2);
    float yv = (xv - mean) * rstd * w[col] + bb[col];
    if (F32OUT) ((float*)outp)[(size_t)token * DD + col] = yv;
    else        ((unsigned short*)outp)[(size_t)token * DD + col] = bf16u(yv);
  }
}

// ---- GEMM: C(M x Nn) = A(M x K) @ W(Nn x K)^T, bf16 inputs, fp32 accum ----
// MODE 0: out bf16 = acc + bias
// MODE 1: out fp32 = acc + bias + pos[(row%196)*Nn + col]   (patch embed)
// MODE 2: out fp32 += acc + bias   (residual; atomicAdd, split-K via gridDim.z)
// MODE 3: out bf16 = gelu(acc + bias)                       (fc1)
template <int MODE>
__global__ __launch_bounds__(256, 4) void gemm_bt(
    const unsigned short* __restrict__ A, const unsigned short* __restrict__ W,
    const float* __restrict__ bias, const float* __restrict__ aux,
    void* __restrict__ outp, int K, int Nn) {
  __shared__ unsigned short As[128 * 32];
  __shared__ unsigned short Bs[128 * 32];
  const int tid = threadIdx.x;
  const int wave = tid >> 6, lane = tid & 63;
  const int tm = blockIdx.y * 128, tn = blockIdx.x * 128;
  const int wm = (wave >> 1) * 64, wn = (wave & 1) * 64;
  const int lr = lane & 15, k8 = (lane >> 4) * 8;
  const int c0 = tid, c1 = tid + 256;          // 16B chunks of the 128x32 tile
  const size_t ga0 = (size_t)(tm + (c0 >> 2)) * K + (c0 & 3) * 8;
  const size_t ga1 = (size_t)(tm + (c1 >> 2)) * K + (c1 & 3) * 8;
  const size_t gb0 = (size_t)(tn + (c0 >> 2)) * K + (c0 & 3) * 8;
  const size_t gb1 = (size_t)(tn + (c1 >> 2)) * K + (c1 & 3) * 8;
  floatx4 acc[4][4] = {};
  const int Ks = K / gridDim.z;                 // split-K segment (z=1 -> full K)
  const int kbeg = blockIdx.z * Ks, kend = kbeg + Ks;
  for (int k0 = kbeg; k0 < kend; k0 += 32) {
    gl2lds16(A + ga0 + k0, &As[c0 * 8]);
    gl2lds16(A + ga1 + k0, &As[c1 * 8]);
    gl2lds16(W + gb0 + k0, &Bs[c0 * 8]);
    gl2lds16(W + gb1 + k0, &Bs[c1 * 8]);
    __syncthreads();
    bf16x8 af[4], bq[4];
#pragma unroll
    for (int mi = 0; mi < 4; mi++)
      af[mi] = *(const bf16x8*)&As[(wm + mi * 16 + lr) * 32 + k8];
#pragma unroll
    for (int ni = 0; ni < 4; ni++)
      bq[ni] = *(const bf16x8*)&Bs[(wn + ni * 16 + lr) * 32 + k8];
#pragma unroll
    for (int mi = 0; mi < 4; mi++)
#pragma unroll
      for (int ni = 0; ni < 4; ni++)
        acc[mi][ni] = mfma_bf16(af[mi], bq[ni], acc[mi][ni]);
    __syncthreads();
  }
  const int rbase = tm + wm + (lane >> 4) * 4;
  const int cbase = tn + wn + lr;
#pragma unroll
  for (int ni = 0; ni < 4; ni++) {
    const int col = cbase + ni * 16;
    const float bv = (MODE == 2 && blockIdx.z != 0) ? 0.f : bias[col];
#pragma unroll
    for (int mi = 0; mi < 4; mi++) {
#pragma unroll
      for (int r = 0; r < 4; r++) {
        const int row = rbase + mi * 16 + r;
        float v = acc[mi][ni][r] + bv;
        if (MODE == 0) {
          ((unsigned short*)outp)[(size_t)row * Nn + col] = bf16u(v);
        } else if (MODE == 1) {
          ((float*)outp)[(size_t)row * Nn + col] =
              v + aux[(size_t)(row % NN) * Nn + col];
        } else if (MODE == 2) {
          float* hp = (float*)outp + (size_t)row * Nn + col;
          atomicAdd(hp, v);
        } else {
          float g = 0.5f * v * (1.0f + erff(v * 0.70710678118654752f));
          ((unsigned short*)outp)[(size_t)row * Nn + col] = bf16u(g);
        }
      }
    }
  }
}

// ---- attention scores: S[bh][i][j] = 0.125 * sum_d Q[b,i,h,d] K[b,j,h,d] ----
__global__ __launch_bounds__(256) void scores_k(const unsigned short* __restrict__ qkv,
                                                float* __restrict__ S) {
  const int bh = blockIdx.x;
  const int b = bh / HH, hh = bh % HH;
  const int i0 = (blockIdx.y / 7) * 32, j0 = (blockIdx.y % 7) * 32;
  const int w = threadIdx.x >> 6, lane = threadIdx.x & 63;
  const int ti = i0 + (w >> 1) * 16, tj = j0 + (w & 1) * 16;
  const int lr = lane & 15, k8 = (lane >> 4) * 8;
  const int iq = min(ti + lr, NN - 1), jk = min(tj + lr, NN - 1);
  const unsigned short* qb = qkv + (size_t)(b * NN + iq) * 2304 + hh * 64 + k8;
  const unsigned short* kb = qkv + (size_t)(b * NN + jk) * 2304 + 768 + hh * 64 + k8;
  floatx4 acc = {0.f, 0.f, 0.f, 0.f};
  acc = mfma_bf16(*(const bf16x8*)qb, *(const bf16x8*)kb, acc);
  acc = mfma_bf16(*(const bf16x8*)(qb + 32), *(const bf16x8*)(kb + 32), acc);
  float* Sb = S + (size_t)bh * NN * NN;
#pragma unroll
  for (int r = 0; r < 4; r++) {
    int i = ti + (lane >> 4) * 4 + r, j = tj + lr;
    if (i < NN && j < NN) Sb[(size_t)i * NN + j] = acc[r] * 0.125f;
  }
}

// ---- softmax rows -> P bf16 padded to 224 cols (zeros past 196) ----
__global__ __launch_bounds__(256) void softmax_k(const float* __restrict__ S,
                                                 unsigned short* __restrict__ P) {
  const int r = blockIdx.x * 4 + (threadIdx.x >> 6);
  const int lane = threadIdx.x & 63;
  const float* row = S + (size_t)r * NN;
  float v[4];
#pragma unroll
  for (int t = 0; t < 4; t++) {
    int j = lane + t * 64;
    v[t] = (j < NN) ? row[j] : -1e30f;
  }
  float m = fmaxf(fmaxf(v[0], v[1]), fmaxf(v[2], v[3]));
#pragma unroll
  for (int off = 32; off; off >>= 1) m = fmaxf(m, __shfl_xor(m, off));
  float e[4], s = 0.f;
#pragma unroll
  for (int t = 0; t < 4; t++) {
    int j = lane + t * 64;
    e[t] = (j < NN) ? __expf(v[t] - m) : 0.f;
    s += e[t];
  }
#pragma unroll
  for (int off = 32; off; off >>= 1) s += __shfl_xor(s, off);
  const float inv = 1.0f / s;
  unsigned short* prow = P + (size_t)r * 224;
#pragma unroll
  for (int t = 0; t < 4; t++) {
    int j = lane + t * 64;
    if (j < 224) prow[j] = bf16u(e[t] * inv);
  }
}

// ---- V transpose: Vt[bh][d][jp] = V[b,j,h,d], zero for j>=196 ----
__global__ __launch_bounds__(256) void vt_k(const unsigned short* __restrict__ qkv,
                                            unsigned short* __restrict__ Vt) {
  int idx = blockIdx.x * 256 + threadIdx.x;     // 384*64*224 exactly
  int j = idx % 224;
  int rest = idx / 224;
  int d = rest % 64, bh = rest / 64;
  int b = bh / HH, hh = bh % HH;
  unsigned short val = 0;
  if (j < NN) val = qkv[(size_t)(b * NN + j) * 2304 + 1536 + hh * 64 + d];
  Vt[idx] = val;
}

// ---- PV: o[b,i, h*64+d] = sum_j P[bh][i][j] * Vt[bh][d][j] ----
__global__ __launch_bounds__(256) void pv_k(const unsigned short* __restrict__ P,
                                            const unsigned short* __restrict__ Vt,
                                            unsigned short* __restrict__ o) {
  const int bh = blockIdx.x;
  const int b = bh / HH, hh = bh % HH;
  const int t = blockIdx.y * 4 + (threadIdx.x >> 6);
  const int it = t >> 2, dt = t & 3;
  const int lane = threadIdx.x & 63, lr = lane & 15, k8 = (lane >> 4) * 8;
  const int ip = min(it * 16 + lr, NN - 1);
  const unsigned short* pb = P + ((size_t)bh * NN + ip) * 224 + k8;
  const unsigned short* vb = Vt + ((size_t)bh * 64 + dt * 16 + lr) * 224 + k8;
  floatx4 acc = {0.f, 0.f, 0.f, 0.f};
#pragma unroll
  for (int k0 = 0; k0 < 224; k0 += 32)
    acc = mfma_bf16(*(const bf16x8*)(pb + k0), *(const bf16x8*)(vb + k0), acc);
#pragma unroll
  for (int r = 0; r < 4; r++) {
    int i = it * 16 + (lane >> 4) * 4 + r;
    if (i < NN)
      o[(size_t)(b * NN + i) * DD + hh * 64 + dt * 16 + lr] = bf16u(acc[r]);
  }
}

extern "C" void kernel_launch(void* const* d_in, const int* in_sizes, int n_in,
                              void* d_out, int out_size, void* d_ws, size_t ws_size,
                              hipStream_t stream) {
  const float* x       = (const float*)d_in[0];
  const float* patchw  = (const float*)d_in[1];
  const float* patchb  = (const float*)d_in[2];
  const float* pos     = (const float*)d_in[3];
  const float* ln1w    = (const float*)d_in[4];
  const float* ln1b    = (const float*)d_in[5];
  const float* qkvw    = (const float*)d_in[6];
  const float* qkvb    = (const float*)d_in[7];
  const float* projw   = (const float*)d_in[8];
  const float* projb   = (const float*)d_in[9];
  const float* ln2w    = (const float*)d_in[10];
  const float* ln2b    = (const float*)d_in[11];
  const float* fc1w    = (const float*)d_in[12];
  const float* fc1b    = (const float*)d_in[13];
  const float* fc2w    = (const float*)d_in[14];
  const float* fc2b    = (const float*)d_in[15];
  const float* lnfw    = (const float*)d_in[16];
  const float* lnfb    = (const float*)d_in[17];

  char* base = (char*)d_ws;
  size_t off = 0;
  auto alloc = [&](size_t bytes) {
    void* p = base + off;
    off = (off + bytes + 255) & ~(size_t)255;
    return p;
  };
  unsigned short* Wq  = (unsigned short*)alloc((size_t)LL * 2304 * 768 * 2);
  unsigned short* Wp  = (unsigned short*)alloc((size_t)LL * 768 * 768 * 2);
  unsigned short* W1  = (unsigned short*)alloc((size_t)LL * 3072 * 768 * 2);
  unsigned short* W2  = (unsigned short*)alloc((size_t)LL * 768 * 3072 * 2);
  unsigned short* Wpe = (unsigned short*)alloc((size_t)768 * 768 * 2);
  float*          h   = (float*)alloc((size_t)MM * DD * 4);
  unsigned short* y   = (unsigned short*)alloc((size_t)MM * DD * 2);
  unsigned short* qkv = (unsigned short*)alloc((size_t)MM * 2304 * 2);
  float*          S   = (float*)alloc((size_t)BHH * NN * NN * 4);   // aliased w/ g
  unsigned short* g   = (unsigned short*)S;                         // fc1 out (38.5MB <= 59MB)
  unsigned short* P   = (unsigned short*)alloc((size_t)BHH * NN * 224 * 2);
  unsigned short* Vt  = (unsigned short*)alloc((size_t)BHH * 64 * 224 * 2);
  unsigned short* o   = (unsigned short*)alloc((size_t)MM * DD * 2);
  if (off > ws_size) return;  // workspace too small: fail loudly (wrong output)

  unsigned short* Aim = qkv;  // im2col buffer aliases qkv (dead by layer 0)

  auto cvt = [&](const float* src, unsigned short* dst, size_t n) {
    int n4 = (int)(n / 4);
    cvt4_k<<<dim3((n4 + 255) / 256), dim3(256), 0, stream>>>(
        (const float4*)src, (ushort4*)dst, n4);
  };
  cvt(qkvw, Wq, (size_t)LL * 2304 * 768);
  cvt(projw, Wp, (size_t)LL * 768 * 768);
  cvt(fc1w, W1, (size_t)LL * 3072 * 768);
  cvt(fc2w, W2, (size_t)LL * 768 * 3072);
  cvt(patchw, Wpe, (size_t)768 * 768);

  im2col_k<<<dim3(MM * DD / 256), dim3(256), 0, stream>>>(x, Aim);
  // patch embed GEMM: h = Aim @ Wpe^T + patch_b + pos
  gemm_bt<1><<<dim3(6, 49, 1), dim3(256), 0, stream>>>(Aim, Wpe, patchb, pos, h, 768, 768);

  for (int l = 0; l < LL; l++) {
    ln_k<0><<<dim3(MM), dim3(256), 0, stream>>>(h, ln1w + l * 768, ln1b + l * 768, y);
    gemm_bt<0><<<dim3(18, 49, 1), dim3(256), 0, stream>>>(
        y, Wq + (size_t)l * 2304 * 768, qkvb + l * 2304, nullptr, qkv, 768, 2304);
    scores_k<<<dim3(BHH, 49), dim3(256), 0, stream>>>(qkv, S);
    softmax_k<<<dim3(BHH * NN / 4), dim3(256), 0, stream>>>(S, P);
    vt_k<<<dim3(BHH * 64 * 224 / 256), dim3(256), 0, stream>>>(qkv, Vt);
    pv_k<<<dim3(BHH, 13), dim3(256), 0, stream>>>(P, Vt, o);
    // proj: split-K x2 -> 588 blocks (was 294), atomicAdd into h
    gemm_bt<2><<<dim3(6, 49, 2), dim3(256), 0, stream>>>(
        o, Wp + (size_t)l * 768 * 768, projb + l * 768, nullptr, h, 768, 768);
    ln_k<0><<<dim3(MM), dim3(256), 0, stream>>>(h, ln2w + l * 768, ln2b + l * 768, y);
    gemm_bt<3><<<dim3(24, 49, 1), dim3(256), 0, stream>>>(
        y, W1 + (size_t)l * 3072 * 768, fc1b + l * 3072, nullptr, g, 768, 3072);
    // fc2: split-K x2 -> 588 blocks, atomicAdd into h
    gemm_bt<2><<<dim3(6, 49, 2), dim3(256), 0, stream>>>(
        g, W2 + (size_t)l * 768 * 3072, fc2b + l * 768, nullptr, h, 3072, 768);
  }
  ln_k<1><<<dim3(MM), dim3(256), 0, stream>>>(h, lnfw, lnfb, d_out);
}

// Round 3
// 4028.185 us; speedup vs baseline: 1.0882x; 1.0696x over previous
//
#include <hip/hip_runtime.h>
#include <hip/hip_bf16.h>
#include <math.h>

// ---- constants ----
#define BB    32
#define DD    768
#define LL    12
#define HH    12
#define NN    196
#define DHH   64
#define FFF   3072
#define MM    (BB * NN)      // 6272 tokens
#define BHH   (BB * HH)      // 384

typedef float  floatx4 __attribute__((ext_vector_type(4)));
typedef __bf16 bf16x8  __attribute__((ext_vector_type(8)));

#define DEV __device__ __forceinline__

DEV unsigned short bf16u(float v) {
  __hip_bfloat16 h = __float2bfloat16(v);
  return __builtin_bit_cast(unsigned short, h);
}

DEV floatx4 mfma_bf16(bf16x8 a, bf16x8 b, floatx4 c) {
  return __builtin_amdgcn_mfma_f32_16x16x32_bf16(a, b, c, 0, 0, 0);
}

DEV void gl2lds16(const void* g, void* l) {
  __builtin_amdgcn_global_load_lds(
      (const __attribute__((address_space(1))) void*)g,
      (__attribute__((address_space(3))) void*)l, 16, 0, 0);
}

// ---- fp32 -> bf16 conversion (vectorized) ----
__global__ __launch_bounds__(256) void cvt4_k(const float4* __restrict__ in,
                                              ushort4* __restrict__ out, int n4) {
  int i = blockIdx.x * 256 + threadIdx.x;
  if (i < n4) {
    float4 v = in[i];
    ushort4 o;
    o.x = bf16u(v.x); o.y = bf16u(v.y); o.z = bf16u(v.z); o.w = bf16u(v.w);
    out[i] = o;
  }
}

// ---- im2col for patch embed: x (32,3,224,224) -> A (6272, 768) bf16 ----
__global__ __launch_bounds__(256) void im2col_k(const float* __restrict__ x,
                                                unsigned short* __restrict__ A) {
  int idx = blockIdx.x * 256 + threadIdx.x;      // grid covers 6272*768 exactly
  int col = idx % DD;
  int token = idx / DD;
  int b = token / NN, p = token % NN;
  int pr = p / 14, pc = p % 14;
  int c = col >> 8, rm = col & 255, i = rm >> 4, j = rm & 15;
  float v = x[(((size_t)b * 3 + c) * 224 + pr * 16 + i) * 224 + pc * 16 + j];
  A[idx] = bf16u(v);
}

// ---- LayerNorm: h fp32 (M,768) -> out (bf16 or fp32) ----
template <int F32OUT>
__global__ __launch_bounds__(256) void ln_k(const float* __restrict__ x,
                                            const float* __restrict__ w,
                                            const float* __restrict__ bb,
                                            void* __restrict__ outp) {
  const int token = blockIdx.x, tid = threadIdx.x;
  const float* xr = x + (size_t)token * DD;
  float v0 = xr[tid], v1 = xr[tid + 256], v2 = xr[tid + 512];
  float s = v0 + v1 + v2;
  float ss = v0 * v0 + v1 * v1 + v2 * v2;
#pragma unroll
  for (int off = 32; off; off >>= 1) {
    s += __shfl_down(s, off);
    ss += __shfl_down(ss, off);
  }
  __shared__ float rs[4], rq[4];
  if ((tid & 63) == 0) { rs[tid >> 6] = s; rq[tid >> 6] = ss; }
  __syncthreads();
  float tot = rs[0] + rs[1] + rs[2] + rs[3];
  float tq  = rq[0] + rq[1] + rq[2] + rq[3];
  const float mean = tot * (1.0f / 768.0f);
  const float var  = tq * (1.0f / 768.0f) - mean * mean;
  const float rstd = rsqrtf(var + 1e-5f);
#pragma unroll
  for (int t = 0; t < 3; t++) {
    int col = tid + t * 256;
    float xv = (t == 0) ? v0 : (t == 1 ? v1 : v2);
    float yv = (xv - mean) * rstd * w[col] + bb[col];
    if (F32OUT) ((float*)outp)[(size_t)token * DD + col] = yv;
    else        ((unsigned short*)outp)[(size_t)token * DD + col] = bf16u(yv);
  }
}

// LDS k-chunk XOR swizzle: LDS slot (row, s) holds global k-chunk s ^ ((row>>1)&3).
// Staging permutes the GLOBAL source (lane->LDS mapping must stay contiguous for
// global_load_lds); reads apply the same XOR. Within a quarter-wave the b128
// fragment reads then spread over 8 banks (2-way, free) instead of 2 (8-way).

// ---- GEMM 128x128: C(M x Nn) = A(M x K) @ W(Nn x K)^T ----
// MODE 0: out bf16 = acc + bias
// MODE 3: out bf16 = gelu(acc + bias)
template <int MODE>
__global__ __launch_bounds__(256, 4) void gemm_bt(
    const unsigned short* __restrict__ A, const unsigned short* __restrict__ W,
    const float* __restrict__ bias, void* __restrict__ outp, int K, int Nn) {
  __shared__ unsigned short As[128 * 32];
  __shared__ unsigned short Bs[128 * 32];
  const int tid = threadIdx.x;
  const int wave = tid >> 6, lane = tid & 63;
  const int tm = blockIdx.y * 128, tn = blockIdx.x * 128;
  const int wm = (wave >> 1) * 64, wn = (wave & 1) * 64;
  const int lr = lane & 15, kq = lane >> 4;
  const int sw = (lr >> 1) & 3;                  // read-side swizzle (row = lr mod relevant bits)
  const int koff = (kq ^ sw) * 8;                // swizzled k-chunk offset in shorts
  const int c0 = tid, c1 = tid + 256;            // staging chunk ids (16B each)
  const int r0 = c0 >> 2, r1 = c1 >> 2;
  const int kc0 = ((c0 & 3) ^ ((r0 >> 1) & 3)) * 8;
  const int kc1 = ((c1 & 3) ^ ((r1 >> 1) & 3)) * 8;
  const size_t ga0 = (size_t)(tm + r0) * K + kc0;
  const size_t ga1 = (size_t)(tm + r1) * K + kc1;
  const size_t gb0 = (size_t)(tn + r0) * K + kc0;
  const size_t gb1 = (size_t)(tn + r1) * K + kc1;
  floatx4 acc[4][4] = {};
  for (int k0 = 0; k0 < K; k0 += 32) {
    gl2lds16(A + ga0 + k0, &As[c0 * 8]);
    gl2lds16(A + ga1 + k0, &As[c1 * 8]);
    gl2lds16(W + gb0 + k0, &Bs[c0 * 8]);
    gl2lds16(W + gb1 + k0, &Bs[c1 * 8]);
    __syncthreads();
    bf16x8 af[4], bq[4];
#pragma unroll
    for (int mi = 0; mi < 4; mi++)
      af[mi] = *(const bf16x8*)&As[(wm + mi * 16 + lr) * 32 + koff];
#pragma unroll
    for (int ni = 0; ni < 4; ni++)
      bq[ni] = *(const bf16x8*)&Bs[(wn + ni * 16 + lr) * 32 + koff];
#pragma unroll
    for (int mi = 0; mi < 4; mi++)
#pragma unroll
      for (int ni = 0; ni < 4; ni++)
        acc[mi][ni] = mfma_bf16(af[mi], bq[ni], acc[mi][ni]);
    __syncthreads();
  }
  const int rbase = tm + wm + (lane >> 4) * 4;
  const int cbase = tn + wn + lr;
#pragma unroll
  for (int ni = 0; ni < 4; ni++) {
    const int col = cbase + ni * 16;
    const float bv = bias[col];
#pragma unroll
    for (int mi = 0; mi < 4; mi++) {
#pragma unroll
      for (int r = 0; r < 4; r++) {
        const int row = rbase + mi * 16 + r;
        float v = acc[mi][ni][r] + bv;
        if (MODE == 0) {
          ((unsigned short*)outp)[(size_t)row * Nn + col] = bf16u(v);
        } else {
          float g = 0.5f * v * (1.0f + erff(v * 0.70710678118654752f));
          ((unsigned short*)outp)[(size_t)row * Nn + col] = bf16u(g);
        }
      }
    }
  }
}

// ---- GEMM 64x128 (more blocks for thin Nn): same math, no atomics ----
// MODE 1: out fp32 = acc + bias + pos[(row%196)*Nn + col]   (patch embed)
// MODE 2: out fp32 = out fp32 + acc + bias                  (residual)
template <int MODE>
__global__ __launch_bounds__(256, 4) void gemm64_bt(
    const unsigned short* __restrict__ A, const unsigned short* __restrict__ W,
    const float* __restrict__ bias, const float* __restrict__ aux,
    float* __restrict__ outp, int K, int Nn) {
  __shared__ unsigned short As[64 * 32];
  __shared__ unsigned short Bs[128 * 32];
  const int tid = threadIdx.x;
  const int wave = tid >> 6, lane = tid & 63;
  const int tm = blockIdx.y * 64, tn = blockIdx.x * 128;
  const int wm = (wave >> 1) * 32, wn = (wave & 1) * 64;
  const int lr = lane & 15, kq = lane >> 4;
  const int sw = (lr >> 1) & 3;
  const int koff = (kq ^ sw) * 8;
  // A: 256 chunks (1/thread); B: 512 chunks (2/thread)
  const int ra = tid >> 2;
  const int kca = ((tid & 3) ^ ((ra >> 1) & 3)) * 8;
  const int c0 = tid, c1 = tid + 256;
  const int r0 = c0 >> 2, r1 = c1 >> 2;
  const int kc0 = ((c0 & 3) ^ ((r0 >> 1) & 3)) * 8;
  const int kc1 = ((c1 & 3) ^ ((r1 >> 1) & 3)) * 8;
  const size_t ga  = (size_t)(tm + ra) * K + kca;
  const size_t gb0 = (size_t)(tn + r0) * K + kc0;
  const size_t gb1 = (size_t)(tn + r1) * K + kc1;
  floatx4 acc[2][4] = {};
  for (int k0 = 0; k0 < K; k0 += 32) {
    gl2lds16(A + ga + k0, &As[tid * 8]);
    gl2lds16(W + gb0 + k0, &Bs[c0 * 8]);
    gl2lds16(W + gb1 + k0, &Bs[c1 * 8]);
    __syncthreads();
    bf16x8 af[2], bq[4];
#pragma unroll
    for (int mi = 0; mi < 2; mi++)
      af[mi] = *(const bf16x8*)&As[(wm + mi * 16 + lr) * 32 + koff];
#pragma unroll
    for (int ni = 0; ni < 4; ni++)
      bq[ni] = *(const bf16x8*)&Bs[(wn + ni * 16 + lr) * 32 + koff];
#pragma unroll
    for (int mi = 0; mi < 2; mi++)
#pragma unroll
      for (int ni = 0; ni < 4; ni++)
        acc[mi][ni] = mfma_bf16(af[mi], bq[ni], acc[mi][ni]);
    __syncthreads();
  }
  const int rbase = tm + wm + (lane >> 4) * 4;
  const int cbase = tn + wn + lr;
#pragma unroll
  for (int ni = 0; ni < 4; ni++) {
    const int col = cbase + ni * 16;
    const float bv = bias[col];
#pragma unroll
    for (int mi = 0; mi < 2; mi++) {
#pragma unroll
      for (int r = 0; r < 4; r++) {
        const int row = rbase + mi * 16 + r;
        float v = acc[mi][ni][r] + bv;
        float* hp = outp + (size_t)row * Nn + col;
        if (MODE == 1) *hp = v + aux[(size_t)(row % NN) * Nn + col];
        else           *hp = *hp + v;
      }
    }
  }
}

// ---- attention scores: S[bh][i][j] = 0.125 * sum_d Q[b,i,h,d] K[b,j,h,d] ----
__global__ __launch_bounds__(256) void scores_k(const unsigned short* __restrict__ qkv,
                                                float* __restrict__ S) {
  const int bh = blockIdx.x;
  const int b = bh / HH, hh = bh % HH;
  const int i0 = (blockIdx.y / 7) * 32, j0 = (blockIdx.y % 7) * 32;
  const int w = threadIdx.x >> 6, lane = threadIdx.x & 63;
  const int ti = i0 + (w >> 1) * 16, tj = j0 + (w & 1) * 16;
  const int lr = lane & 15, k8 = (lane >> 4) * 8;
  const int iq = min(ti + lr, NN - 1), jk = min(tj + lr, NN - 1);
  const unsigned short* qb = qkv + (size_t)(b * NN + iq) * 2304 + hh * 64 + k8;
  const unsigned short* kb = qkv + (size_t)(b * NN + jk) * 2304 + 768 + hh * 64 + k8;
  floatx4 acc = {0.f, 0.f, 0.f, 0.f};
  acc = mfma_bf16(*(const bf16x8*)qb, *(const bf16x8*)kb, acc);
  acc = mfma_bf16(*(const bf16x8*)(qb + 32), *(const bf16x8*)(kb + 32), acc);
  float* Sb = S + (size_t)bh * NN * NN;
#pragma unroll
  for (int r = 0; r < 4; r++) {
    int i = ti + (lane >> 4) * 4 + r, j = tj + lr;
    if (i < NN && j < NN) Sb[(size_t)i * NN + j] = acc[r] * 0.125f;
  }
}

// ---- softmax rows -> P bf16 padded to 224 cols (zeros past 196) ----
__global__ __launch_bounds__(256) void softmax_k(const float* __restrict__ S,
                                                 unsigned short* __restrict__ P) {
  const int r = blockIdx.x * 4 + (threadIdx.x >> 6);
  const int lane = threadIdx.x & 63;
  const float* row = S + (size_t)r * NN;
  float v[4];
#pragma unroll
  for (int t = 0; t < 4; t++) {
    int j = lane + t * 64;
    v[t] = (j < NN) ? row[j] : -1e30f;
  }
  float m = fmaxf(fmaxf(v[0], v[1]), fmaxf(v[2], v[3]));
#pragma unroll
  for (int off = 32; off; off >>= 1) m = fmaxf(m, __shfl_xor(m, off));
  float e[4], s = 0.f;
#pragma unroll
  for (int t = 0; t < 4; t++) {
    int j = lane + t * 64;
    e[t] = (j < NN) ? __expf(v[t] - m) : 0.f;
    s += e[t];
  }
#pragma unroll
  for (int off = 32; off; off >>= 1) s += __shfl_xor(s, off);
  const float inv = 1.0f / s;
  unsigned short* prow = P + (size_t)r * 224;
#pragma unroll
  for (int t = 0; t < 4; t++) {
    int j = lane + t * 64;
    if (j < 224) prow[j] = bf16u(e[t] * inv);
  }
}

// ---- V transpose: Vt[bh][d][jp] = V[b,j,h,d], zero for j>=196 ----
__global__ __launch_bounds__(256) void vt_k(const unsigned short* __restrict__ qkv,
                                            unsigned short* __restrict__ Vt) {
  int idx = blockIdx.x * 256 + threadIdx.x;     // 384*64*224 exactly
  int j = idx % 224;
  int rest = idx / 224;
  int d = rest % 64, bh = rest / 64;
  int b = bh / HH, hh = bh % HH;
  unsigned short val = 0;
  if (j < NN) val = qkv[(size_t)(b * NN + j) * 2304 + 1536 + hh * 64 + d];
  Vt[idx] = val;
}

// ---- PV: o[b,i, h*64+d] = sum_j P[bh][i][j] * Vt[bh][d][j] ----
__global__ __launch_bounds__(256) void pv_k(const unsigned short* __restrict__ P,
                                            const unsigned short* __restrict__ Vt,
                                            unsigned short* __restrict__ o) {
  const int bh = blockIdx.x;
  const int b = bh / HH, hh = bh % HH;
  const int t = blockIdx.y * 4 + (threadIdx.x >> 6);
  const int it = t >> 2, dt = t & 3;
  const int lane = threadIdx.x & 63, lr = lane & 15, k8 = (lane >> 4) * 8;
  const int ip = min(it * 16 + lr, NN - 1);
  const unsigned short* pb = P + ((size_t)bh * NN + ip) * 224 + k8;
  const unsigned short* vb = Vt + ((size_t)bh * 64 + dt * 16 + lr) * 224 + k8;
  floatx4 acc = {0.f, 0.f, 0.f, 0.f};
#pragma unroll
  for (int k0 = 0; k0 < 224; k0 += 32)
    acc = mfma_bf16(*(const bf16x8*)(pb + k0), *(const bf16x8*)(vb + k0), acc);
#pragma unroll
  for (int r = 0; r < 4; r++) {
    int i = it * 16 + (lane >> 4) * 4 + r;
    if (i < NN)
      o[(size_t)(b * NN + i) * DD + hh * 64 + dt * 16 + lr] = bf16u(acc[r]);
  }
}

extern "C" void kernel_launch(void* const* d_in, const int* in_sizes, int n_in,
                              void* d_out, int out_size, void* d_ws, size_t ws_size,
                              hipStream_t stream) {
  const float* x       = (const float*)d_in[0];
  const float* patchw  = (const float*)d_in[1];
  const float* patchb  = (const float*)d_in[2];
  const float* pos     = (const float*)d_in[3];
  const float* ln1w    = (const float*)d_in[4];
  const float* ln1b    = (const float*)d_in[5];
  const float* qkvw    = (const float*)d_in[6];
  const float* qkvb    = (const float*)d_in[7];
  const float* projw   = (const float*)d_in[8];
  const float* projb   = (const float*)d_in[9];
  const float* ln2w    = (const float*)d_in[10];
  const float* ln2b    = (const float*)d_in[11];
  const float* fc1w    = (const float*)d_in[12];
  const float* fc1b    = (const float*)d_in[13];
  const float* fc2w    = (const float*)d_in[14];
  const float* fc2b    = (const float*)d_in[15];
  const float* lnfw    = (const float*)d_in[16];
  const float* lnfb    = (const float*)d_in[17];

  char* base = (char*)d_ws;
  size_t off = 0;
  auto alloc = [&](size_t bytes) {
    void* p = base + off;
    off = (off + bytes + 255) & ~(size_t)255;
    return p;
  };
  unsigned short* Wq  = (unsigned short*)alloc((size_t)LL * 2304 * 768 * 2);
  unsigned short* Wp  = (unsigned short*)alloc((size_t)LL * 768 * 768 * 2);
  unsigned short* W1  = (unsigned short*)alloc((size_t)LL * 3072 * 768 * 2);
  unsigned short* W2  = (unsigned short*)alloc((size_t)LL * 768 * 3072 * 2);
  unsigned short* Wpe = (unsigned short*)alloc((size_t)768 * 768 * 2);
  float*          h   = (float*)alloc((size_t)MM * DD * 4);
  unsigned short* y   = (unsigned short*)alloc((size_t)MM * DD * 2);
  unsigned short* qkv = (unsigned short*)alloc((size_t)MM * 2304 * 2);
  float*          S   = (float*)alloc((size_t)BHH * NN * NN * 4);   // aliased w/ g
  unsigned short* g   = (unsigned short*)S;                         // fc1 out (38.5MB <= 59MB)
  unsigned short* P   = (unsigned short*)alloc((size_t)BHH * NN * 224 * 2);
  unsigned short* Vt  = (unsigned short*)alloc((size_t)BHH * 64 * 224 * 2);
  unsigned short* o   = (unsigned short*)alloc((size_t)MM * DD * 2);
  if (off > ws_size) return;  // workspace too small: fail loudly (wrong output)

  unsigned short* Aim = qkv;  // im2col buffer aliases qkv (dead by layer 0)

  auto cvt = [&](const float* src, unsigned short* dst, size_t n) {
    int n4 = (int)(n / 4);
    cvt4_k<<<dim3((n4 + 255) / 256), dim3(256), 0, stream>>>(
        (const float4*)src, (ushort4*)dst, n4);
  };
  cvt(qkvw, Wq, (size_t)LL * 2304 * 768);
  cvt(projw, Wp, (size_t)LL * 768 * 768);
  cvt(fc1w, W1, (size_t)LL * 3072 * 768);
  cvt(fc2w, W2, (size_t)LL * 768 * 3072);
  cvt(patchw, Wpe, (size_t)768 * 768);

  im2col_k<<<dim3(MM * DD / 256), dim3(256), 0, stream>>>(x, Aim);
  // patch embed GEMM: h = Aim @ Wpe^T + patch_b + pos   (64x128 tiles, 588 blocks)
  gemm64_bt<1><<<dim3(6, 98), dim3(256), 0, stream>>>(Aim, Wpe, patchb, pos, h, 768, 768);

  for (int l = 0; l < LL; l++) {
    ln_k<0><<<dim3(MM), dim3(256), 0, stream>>>(h, ln1w + l * 768, ln1b + l * 768, y);
    gemm_bt<0><<<dim3(18, 49), dim3(256), 0, stream>>>(
        y, Wq + (size_t)l * 2304 * 768, qkvb + l * 2304, qkv, 768, 2304);
    scores_k<<<dim3(BHH, 49), dim3(256), 0, stream>>>(qkv, S);
    softmax_k<<<dim3(BHH * NN / 4), dim3(256), 0, stream>>>(S, P);
    vt_k<<<dim3(BHH * 64 * 224 / 256), dim3(256), 0, stream>>>(qkv, Vt);
    pv_k<<<dim3(BHH, 13), dim3(256), 0, stream>>>(P, Vt, o);
    // proj: 64x128 tiles -> 588 blocks, residual read-add-write (no atomics)
    gemm64_bt<2><<<dim3(6, 98), dim3(256), 0, stream>>>(
        o, Wp + (size_t)l * 768 * 768, projb + l * 768, nullptr, h, 768, 768);
    ln_k<0><<<dim3(MM), dim3(256), 0, stream>>>(h, ln2w + l * 768, ln2b + l * 768, y);
    gemm_bt<3><<<dim3(24, 49), dim3(256), 0, stream>>>(
        y, W1 + (size_t)l * 3072 * 768, fc1b + l * 3072, g, 768, 3072);
    // fc2: 64x128 tiles -> 588 blocks, residual read-add-write
    gemm64_bt<2><<<dim3(6, 98), dim3(256), 0, stream>>>(
        g, W2 + (size_t)l * 768 * 3072, fc2b + l * 768, nullptr, h, 3072, 768);
  }
  ln_k<1><<<dim3(MM), dim3(256), 0, stream>>>(h, lnfw, lnfb, d_out);
}

// Round 4
// 3923.007 us; speedup vs baseline: 1.1174x; 1.0268x over previous
//
#include <hip/hip_runtime.h>
#include <hip/hip_bf16.h>
#include <math.h>

// ---- constants ----
#define BB    32
#define DD    768
#define LL    12
#define HH    12
#define NN    196
#define DHH   64
#define FFF   3072
#define MM    (BB * NN)      // 6272 tokens
#define BHH   (BB * HH)      // 384

typedef float  floatx4 __attribute__((ext_vector_type(4)));
typedef __bf16 bf16x8  __attribute__((ext_vector_type(8)));

#define DEV __device__ __forceinline__

DEV unsigned short bf16u(float v) {
  __hip_bfloat16 h = __float2bfloat16(v);
  return __builtin_bit_cast(unsigned short, h);
}

DEV floatx4 mfma_bf16(bf16x8 a, bf16x8 b, floatx4 c) {
  return __builtin_amdgcn_mfma_f32_16x16x32_bf16(a, b, c, 0, 0, 0);
}

DEV void gl2lds16(const void* g, void* l) {
  __builtin_amdgcn_global_load_lds(
      (const __attribute__((address_space(1))) void*)g,
      (__attribute__((address_space(3))) void*)l, 16, 0, 0);
}

// ---- fp32 -> bf16 conversion (vectorized) ----
__global__ __launch_bounds__(256) void cvt4_k(const float4* __restrict__ in,
                                              ushort4* __restrict__ out, int n4) {
  int i = blockIdx.x * 256 + threadIdx.x;
  if (i < n4) {
    float4 v = in[i];
    ushort4 o;
    o.x = bf16u(v.x); o.y = bf16u(v.y); o.z = bf16u(v.z); o.w = bf16u(v.w);
    out[i] = o;
  }
}

// ---- im2col for patch embed: x (32,3,224,224) -> A (6272, 768) bf16 ----
__global__ __launch_bounds__(256) void im2col_k(const float* __restrict__ x,
                                                unsigned short* __restrict__ A) {
  int idx = blockIdx.x * 256 + threadIdx.x;      // grid covers 6272*768 exactly
  int col = idx % DD;
  int token = idx / DD;
  int b = token / NN, p = token % NN;
  int pr = p / 14, pc = p % 14;
  int c = col >> 8, rm = col & 255, i = rm >> 4, j = rm & 15;
  float v = x[(((size_t)b * 3 + c) * 224 + pr * 16 + i) * 224 + pc * 16 + j];
  A[idx] = bf16u(v);
}

// ---- LayerNorm: h fp32 (M,768) -> out (bf16 or fp32) ----
template <int F32OUT>
__global__ __launch_bounds__(256) void ln_k(const float* __restrict__ x,
                                            const float* __restrict__ w,
                                            const float* __restrict__ bb,
                                            void* __restrict__ outp) {
  const int token = blockIdx.x, tid = threadIdx.x;
  const float* xr = x + (size_t)token * DD;
  float v0 = xr[tid], v1 = xr[tid + 256], v2 = xr[tid + 512];
  float s = v0 + v1 + v2;
  float ss = v0 * v0 + v1 * v1 + v2 * v2;
#pragma unroll
  for (int off = 32; off; off >>= 1) {
    s += __shfl_down(s, off);
    ss += __shfl_down(ss, off);
  }
  __shared__ float rs[4], rq[4];
  if ((tid & 63) == 0) { rs[tid >> 6] = s; rq[tid >> 6] = ss; }
  __syncthreads();
  float tot = rs[0] + rs[1] + rs[2] + rs[3];
  float tq  = rq[0] + rq[1] + rq[2] + rq[3];
  const float mean = tot * (1.0f / 768.0f);
  const float var  = tq * (1.0f / 768.0f) - mean * mean;
  const float rstd = rsqrtf(var + 1e-5f);
#pragma unroll
  for (int t = 0; t < 3; t++) {
    int col = tid + t * 256;
    float xv = (t == 0) ? v0 : (t == 1 ? v1 : v2);
    float yv = (xv - mean) * rstd * w[col] + bb[col];
    if (F32OUT) ((float*)outp)[(size_t)token * DD + col] = yv;
    else        ((unsigned short*)outp)[(size_t)token * DD + col] = bf16u(yv);
  }
}

// LDS k-chunk XOR swizzle (R3, verified: conflicts -> 0): LDS slot (row,s)
// holds global k-chunk s ^ ((row>>1)&3); staging permutes the GLOBAL source,
// reads apply the same XOR.

// ---- GEMM 128x128, double-buffered LDS ----
// MODE 0: out bf16 = acc + bias
// MODE 3: out bf16 = gelu(acc + bias)
template <int MODE>
__global__ __launch_bounds__(256, 4) void gemm_bt(
    const unsigned short* __restrict__ A, const unsigned short* __restrict__ W,
    const float* __restrict__ bias, void* __restrict__ outp, int K, int Nn) {
  __shared__ unsigned short As[2][128 * 32];
  __shared__ unsigned short Bs[2][128 * 32];
  const int tid = threadIdx.x;
  const int wave = tid >> 6, lane = tid & 63;
  const int tm = blockIdx.y * 128, tn = blockIdx.x * 128;
  const int wm = (wave >> 1) * 64, wn = (wave & 1) * 64;
  const int lr = lane & 15, kq = lane >> 4;
  const int sw = (lr >> 1) & 3;
  const int koff = (kq ^ sw) * 8;
  const int c0 = tid, c1 = tid + 256;
  const int r0 = c0 >> 2, r1 = c1 >> 2;
  const int kc0 = ((c0 & 3) ^ ((r0 >> 1) & 3)) * 8;
  const int kc1 = ((c1 & 3) ^ ((r1 >> 1) & 3)) * 8;
  const size_t ga0 = (size_t)(tm + r0) * K + kc0;
  const size_t ga1 = (size_t)(tm + r1) * K + kc1;
  const size_t gb0 = (size_t)(tn + r0) * K + kc0;
  const size_t gb1 = (size_t)(tn + r1) * K + kc1;
  floatx4 acc[4][4] = {};
  auto stage = [&](int buf, int k0) {
    gl2lds16(A + ga0 + k0, &As[buf][c0 * 8]);
    gl2lds16(A + ga1 + k0, &As[buf][c1 * 8]);
    gl2lds16(W + gb0 + k0, &Bs[buf][c0 * 8]);
    gl2lds16(W + gb1 + k0, &Bs[buf][c1 * 8]);
  };
  const int nk = K >> 5;
  stage(0, 0);
  for (int it = 0; it < nk; it++) {
    const int cur = it & 1;
    __syncthreads();                       // drains stage(cur) (issued last iter)
    if (it + 1 < nk) stage(cur ^ 1, (it + 1) << 5);
    bf16x8 af[4], bq[4];
#pragma unroll
    for (int mi = 0; mi < 4; mi++)
      af[mi] = *(const bf16x8*)&As[cur][(wm + mi * 16 + lr) * 32 + koff];
#pragma unroll
    for (int ni = 0; ni < 4; ni++)
      bq[ni] = *(const bf16x8*)&Bs[cur][(wn + ni * 16 + lr) * 32 + koff];
#pragma unroll
    for (int mi = 0; mi < 4; mi++)
#pragma unroll
      for (int ni = 0; ni < 4; ni++)
        acc[mi][ni] = mfma_bf16(af[mi], bq[ni], acc[mi][ni]);
  }
  const int rbase = tm + wm + (lane >> 4) * 4;
  const int cbase = tn + wn + lr;
#pragma unroll
  for (int ni = 0; ni < 4; ni++) {
    const int col = cbase + ni * 16;
    const float bv = bias[col];
#pragma unroll
    for (int mi = 0; mi < 4; mi++) {
#pragma unroll
      for (int r = 0; r < 4; r++) {
        const int row = rbase + mi * 16 + r;
        float v = acc[mi][ni][r] + bv;
        if (MODE == 0) {
          ((unsigned short*)outp)[(size_t)row * Nn + col] = bf16u(v);
        } else {
          float g = 0.5f * v * (1.0f + erff(v * 0.70710678118654752f));
          ((unsigned short*)outp)[(size_t)row * Nn + col] = bf16u(g);
        }
      }
    }
  }
}

// ---- GEMM 64x128, double-buffered LDS (thin-N residual GEMMs) ----
// MODE 1: out fp32 = acc + bias + pos[(row%196)*Nn + col]   (patch embed)
// MODE 2: out fp32 = out fp32 + acc + bias                  (residual)
template <int MODE>
__global__ __launch_bounds__(256, 4) void gemm64_bt(
    const unsigned short* __restrict__ A, const unsigned short* __restrict__ W,
    const float* __restrict__ bias, const float* __restrict__ aux,
    float* __restrict__ outp, int K, int Nn) {
  __shared__ unsigned short As[2][64 * 32];
  __shared__ unsigned short Bs[2][128 * 32];
  const int tid = threadIdx.x;
  const int wave = tid >> 6, lane = tid & 63;
  const int tm = blockIdx.y * 64, tn = blockIdx.x * 128;
  const int wm = (wave >> 1) * 32, wn = (wave & 1) * 64;
  const int lr = lane & 15, kq = lane >> 4;
  const int sw = (lr >> 1) & 3;
  const int koff = (kq ^ sw) * 8;
  const int ra = tid >> 2;
  const int kca = ((tid & 3) ^ ((ra >> 1) & 3)) * 8;
  const int c0 = tid, c1 = tid + 256;
  const int r0 = c0 >> 2, r1 = c1 >> 2;
  const int kc0 = ((c0 & 3) ^ ((r0 >> 1) & 3)) * 8;
  const int kc1 = ((c1 & 3) ^ ((r1 >> 1) & 3)) * 8;
  const size_t ga  = (size_t)(tm + ra) * K + kca;
  const size_t gb0 = (size_t)(tn + r0) * K + kc0;
  const size_t gb1 = (size_t)(tn + r1) * K + kc1;
  floatx4 acc[2][4] = {};
  auto stage = [&](int buf, int k0) {
    gl2lds16(A + ga + k0, &As[buf][tid * 8]);
    gl2lds16(W + gb0 + k0, &Bs[buf][c0 * 8]);
    gl2lds16(W + gb1 + k0, &Bs[buf][c1 * 8]);
  };
  const int nk = K >> 5;
  stage(0, 0);
  for (int it = 0; it < nk; it++) {
    const int cur = it & 1;
    __syncthreads();
    if (it + 1 < nk) stage(cur ^ 1, (it + 1) << 5);
    bf16x8 af[2], bq[4];
#pragma unroll
    for (int mi = 0; mi < 2; mi++)
      af[mi] = *(const bf16x8*)&As[cur][(wm + mi * 16 + lr) * 32 + koff];
#pragma unroll
    for (int ni = 0; ni < 4; ni++)
      bq[ni] = *(const bf16x8*)&Bs[cur][(wn + ni * 16 + lr) * 32 + koff];
#pragma unroll
    for (int mi = 0; mi < 2; mi++)
#pragma unroll
      for (int ni = 0; ni < 4; ni++)
        acc[mi][ni] = mfma_bf16(af[mi], bq[ni], acc[mi][ni]);
  }
  const int rbase = tm + wm + (lane >> 4) * 4;
  const int cbase = tn + wn + lr;
#pragma unroll
  for (int ni = 0; ni < 4; ni++) {
    const int col = cbase + ni * 16;
    const float bv = bias[col];
#pragma unroll
    for (int mi = 0; mi < 2; mi++) {
#pragma unroll
      for (int r = 0; r < 4; r++) {
        const int row = rbase + mi * 16 + r;
        float v = acc[mi][ni][r] + bv;
        float* hp = outp + (size_t)row * Nn + col;
        if (MODE == 1) *hp = v + aux[(size_t)(row % NN) * Nn + col];
        else           *hp = *hp + v;
      }
    }
  }
}

// ---- fused scores+softmax: per (bh, 32-row Q tile) -> P bf16 (rows x 224) ----
__global__ __launch_bounds__(256) void attn_sm_k(const unsigned short* __restrict__ qkv,
                                                 unsigned short* __restrict__ P) {
  __shared__ float S[32][232];             // +8 pad
  const int tid = threadIdx.x;
  const int bh = blockIdx.x;
  const int b = bh / HH, hh = bh % HH;
  const int i0 = blockIdx.y * 32;
  const int wave = tid >> 6, lane = tid & 63;
  const int lr = lane & 15, k8 = (lane >> 4) * 8;
  // 2x14 grid of 16x16 S tiles, 7 per wave
  for (int t = wave; t < 28; t += 4) {
    const int til = (t / 14) * 16, tj = (t % 14) * 16;
    const int iq = min(i0 + til + lr, NN - 1), jk = min(tj + lr, NN - 1);
    const unsigned short* qb = qkv + (size_t)(b * NN + iq) * 2304 + hh * 64 + k8;
    const unsigned short* kb = qkv + (size_t)(b * NN + jk) * 2304 + 768 + hh * 64 + k8;
    floatx4 acc = {0.f, 0.f, 0.f, 0.f};
    acc = mfma_bf16(*(const bf16x8*)qb, *(const bf16x8*)kb, acc);
    acc = mfma_bf16(*(const bf16x8*)(qb + 32), *(const bf16x8*)(kb + 32), acc);
#pragma unroll
    for (int r = 0; r < 4; r++)
      S[til + (lane >> 4) * 4 + r][tj + lr] = acc[r] * 0.125f;
  }
  __syncthreads();
  // softmax: 8 threads per row (row = tid>>3), cols strided by 8
  const int row = tid >> 3, sub = tid & 7;
  float v[28];
  float m = -1e30f;
#pragma unroll
  for (int t = 0; t < 28; t++) {
    const int c = sub + t * 8;
    v[t] = (c < NN) ? S[row][c] : -1e30f;
    m = fmaxf(m, v[t]);
  }
  m = fmaxf(m, __shfl_xor(m, 1));
  m = fmaxf(m, __shfl_xor(m, 2));
  m = fmaxf(m, __shfl_xor(m, 4));
  float s = 0.f;
#pragma unroll
  for (int t = 0; t < 28; t++) {
    v[t] = (sub + t * 8 < NN) ? __expf(v[t] - m) : 0.f;
    s += v[t];
  }
  s += __shfl_xor(s, 1);
  s += __shfl_xor(s, 2);
  s += __shfl_xor(s, 4);
  const float inv = 1.0f / s;
  const int gi = i0 + row;
  if (gi < NN) {
    unsigned short* prow = P + ((size_t)bh * NN + gi) * 224;
#pragma unroll
    for (int t = 0; t < 28; t++) prow[sub + t * 8] = bf16u(v[t] * inv);
  }
}

// ---- V transpose: Vt[bh][d][jp] = V[b,j,h,d], zero for j>=196 ----
__global__ __launch_bounds__(256) void vt_k(const unsigned short* __restrict__ qkv,
                                            unsigned short* __restrict__ Vt) {
  int idx = blockIdx.x * 256 + threadIdx.x;     // 384*64*224 exactly
  int j = idx % 224;
  int rest = idx / 224;
  int d = rest % 64, bh = rest / 64;
  int b = bh / HH, hh = bh % HH;
  unsigned short val = 0;
  if (j < NN) val = qkv[(size_t)(b * NN + j) * 2304 + 1536 + hh * 64 + d];
  Vt[idx] = val;
}

// ---- PV: o[b,i, h*64+d] = sum_j P[bh][i][j] * Vt[bh][d][j] ----
__global__ __launch_bounds__(256) void pv_k(const unsigned short* __restrict__ P,
                                            const unsigned short* __restrict__ Vt,
                                            unsigned short* __restrict__ o) {
  const int bh = blockIdx.x;
  const int b = bh / HH, hh = bh % HH;
  const int t = blockIdx.y * 4 + (threadIdx.x >> 6);
  const int it = t >> 2, dt = t & 3;
  const int lane = threadIdx.x & 63, lr = lane & 15, k8 = (lane >> 4) * 8;
  const int ip = min(it * 16 + lr, NN - 1);
  const unsigned short* pb = P + ((size_t)bh * NN + ip) * 224 + k8;
  const unsigned short* vb = Vt + ((size_t)bh * 64 + dt * 16 + lr) * 224 + k8;
  floatx4 acc = {0.f, 0.f, 0.f, 0.f};
#pragma unroll
  for (int k0 = 0; k0 < 224; k0 += 32)
    acc = mfma_bf16(*(const bf16x8*)(pb + k0), *(const bf16x8*)(vb + k0), acc);
#pragma unroll
  for (int r = 0; r < 4; r++) {
    int i = it * 16 + (lane >> 4) * 4 + r;
    if (i < NN)
      o[(size_t)(b * NN + i) * DD + hh * 64 + dt * 16 + lr] = bf16u(acc[r]);
  }
}

extern "C" void kernel_launch(void* const* d_in, const int* in_sizes, int n_in,
                              void* d_out, int out_size, void* d_ws, size_t ws_size,
                              hipStream_t stream) {
  const float* x       = (const float*)d_in[0];
  const float* patchw  = (const float*)d_in[1];
  const float* patchb  = (const float*)d_in[2];
  const float* pos     = (const float*)d_in[3];
  const float* ln1w    = (const float*)d_in[4];
  const float* ln1b    = (const float*)d_in[5];
  const float* qkvw    = (const float*)d_in[6];
  const float* qkvb    = (const float*)d_in[7];
  const float* projw   = (const float*)d_in[8];
  const float* projb   = (const float*)d_in[9];
  const float* ln2w    = (const float*)d_in[10];
  const float* ln2b    = (const float*)d_in[11];
  const float* fc1w    = (const float*)d_in[12];
  const float* fc1b    = (const float*)d_in[13];
  const float* fc2w    = (const float*)d_in[14];
  const float* fc2b    = (const float*)d_in[15];
  const float* lnfw    = (const float*)d_in[16];
  const float* lnfb    = (const float*)d_in[17];

  char* base = (char*)d_ws;
  size_t off = 0;
  auto alloc = [&](size_t bytes) {
    void* p = base + off;
    off = (off + bytes + 255) & ~(size_t)255;
    return p;
  };
  unsigned short* Wq  = (unsigned short*)alloc((size_t)LL * 2304 * 768 * 2);
  unsigned short* Wp  = (unsigned short*)alloc((size_t)LL * 768 * 768 * 2);
  unsigned short* W1  = (unsigned short*)alloc((size_t)LL * 3072 * 768 * 2);
  unsigned short* W2  = (unsigned short*)alloc((size_t)LL * 768 * 3072 * 2);
  unsigned short* Wpe = (unsigned short*)alloc((size_t)768 * 768 * 2);
  float*          h   = (float*)alloc((size_t)MM * DD * 4);
  unsigned short* y   = (unsigned short*)alloc((size_t)MM * DD * 2);
  unsigned short* qkv = (unsigned short*)alloc((size_t)MM * 2304 * 2);
  unsigned short* g   = (unsigned short*)alloc((size_t)MM * FFF * 2);  // fc1 out
  unsigned short* P   = (unsigned short*)alloc((size_t)BHH * NN * 224 * 2);
  unsigned short* Vt  = (unsigned short*)alloc((size_t)BHH * 64 * 224 * 2);
  unsigned short* o   = (unsigned short*)alloc((size_t)MM * DD * 2);
  if (off > ws_size) return;  // workspace too small: fail loudly (wrong output)

  unsigned short* Aim = qkv;  // im2col buffer aliases qkv (dead by layer 0)

  auto cvt = [&](const float* src, unsigned short* dst, size_t n) {
    int n4 = (int)(n / 4);
    cvt4_k<<<dim3((n4 + 255) / 256), dim3(256), 0, stream>>>(
        (const float4*)src, (ushort4*)dst, n4);
  };
  cvt(qkvw, Wq, (size_t)LL * 2304 * 768);
  cvt(projw, Wp, (size_t)LL * 768 * 768);
  cvt(fc1w, W1, (size_t)LL * 3072 * 768);
  cvt(fc2w, W2, (size_t)LL * 768 * 3072);
  cvt(patchw, Wpe, (size_t)768 * 768);

  im2col_k<<<dim3(MM * DD / 256), dim3(256), 0, stream>>>(x, Aim);
  // patch embed GEMM: h = Aim @ Wpe^T + patch_b + pos
  gemm64_bt<1><<<dim3(6, 98), dim3(256), 0, stream>>>(Aim, Wpe, patchb, pos, h, 768, 768);

  for (int l = 0; l < LL; l++) {
    ln_k<0><<<dim3(MM), dim3(256), 0, stream>>>(h, ln1w + l * 768, ln1b + l * 768, y);
    gemm_bt<0><<<dim3(18, 49), dim3(256), 0, stream>>>(
        y, Wq + (size_t)l * 2304 * 768, qkvb + l * 2304, qkv, 768, 2304);
    attn_sm_k<<<dim3(BHH, 7), dim3(256), 0, stream>>>(qkv, P);
    vt_k<<<dim3(BHH * 64 * 224 / 256), dim3(256), 0, stream>>>(qkv, Vt);
    pv_k<<<dim3(BHH, 13), dim3(256), 0, stream>>>(P, Vt, o);
    gemm64_bt<2><<<dim3(6, 98), dim3(256), 0, stream>>>(
        o, Wp + (size_t)l * 768 * 768, projb + l * 768, nullptr, h, 768, 768);
    ln_k<0><<<dim3(MM), dim3(256), 0, stream>>>(h, ln2w + l * 768, ln2b + l * 768, y);
    gemm_bt<3><<<dim3(24, 49), dim3(256), 0, stream>>>(
        y, W1 + (size_t)l * 3072 * 768, fc1b + l * 3072, g, 768, 3072);
    gemm64_bt<2><<<dim3(6, 98), dim3(256), 0, stream>>>(
        g, W2 + (size_t)l * 768 * 3072, fc2b + l * 768, nullptr, h, 3072, 768);
  }
  ln_k<1><<<dim3(MM), dim3(256), 0, stream>>>(h, lnfw, lnfb, d_out);
}